// Round 8
// baseline (364.512 us; speedup 1.0000x reference)
//
#include <hip/hip_runtime.h>

#define NN 50000
#define NE 800000
#define NB 512
#define DIN 128
#define DD2 200
#define C1 100
#define C2 20
#define DHH 64
#define HH1 128
#define HH2 32
#define KD 201      // fusion inner dim per i (200 + 1)
#define KDP 204     // padded row stride for d1ext
#define NU 2688     // 21 * 128

__device__ __forceinline__ unsigned short f2bf(float x) {
    unsigned u = __float_as_uint(x);
    unsigned r = (u + 0x7fffu + ((u >> 16) & 1u)) >> 16;   // RNE
    return (unsigned short)r;
}
__device__ __forceinline__ float bf_lo(unsigned u) { return __uint_as_float(u << 16); }
__device__ __forceinline__ float bf_hi(unsigned u) { return __uint_as_float(u & 0xffff0000u); }

// ---------------- graph build: lock-free per-node edge list ----------------
// head[n] = last edge id targeting n (-1 none); next[e] = previous edge id.
__global__ void k_build(const int* __restrict__ dst, int* __restrict__ head,
                        int* __restrict__ next) {
    int e = blockIdx.x * 256 + threadIdx.x;
    if (e < NE) {
        int prev = atomicExch(&head[dst[e]], e);
        next[e] = prev;
    }
}

// ---------------- GCN layer 1 GEMM ----------------
// t1b[n][j] = packed bf16 pair (channels 2j, 2j+1) of feat@gc1_W
__global__ __launch_bounds__(256, 2) void k_gemm1(const float* __restrict__ feat,
                                                  const float* __restrict__ W,
                                                  unsigned* __restrict__ t1b) {
    __shared__ float sWT[C1 * DIN];      // sWT[col*128 + (k ^ ((col&7)<<2))]
    __shared__ float sf[32][DIN + 4];
    const int tid = threadIdx.x;
    for (int idx = tid; idx < DIN * C1; idx += 256) {
        int k = idx / C1, col = idx % C1;
        sWT[col * DIN + (k ^ ((col & 7) << 2))] = W[idx];
    }
    const int j = tid & 63;              // active j<50: cols 2j, 2j+1
    const int rg = tid >> 6;             // 0..3
    const bool act = j < 50;
    const int c0 = 2 * j, c1 = 2 * j + 1;
    const int swz0 = (c0 & 7) << 2, swz1 = (c1 & 7) << 2;

    for (int n0 = blockIdx.x * 32; n0 < NN; n0 += gridDim.x * 32) {
        __syncthreads();
        {
            int r = tid >> 3, so = (tid & 7) * 16;
            int n = n0 + r;
            float4* dstp = (float4*)&sf[r][so];
            if (n < NN) {
                const float4* srcp = (const float4*)(feat + (size_t)n * DIN + so);
                dstp[0] = srcp[0]; dstp[1] = srcp[1]; dstp[2] = srcp[2]; dstp[3] = srcp[3];
            } else {
                float4 z = {0.f, 0.f, 0.f, 0.f};
                dstp[0] = z; dstp[1] = z; dstp[2] = z; dstp[3] = z;
            }
        }
        __syncthreads();
        if (act) {
            float acc0[8], acc1[8];
            #pragma unroll
            for (int r = 0; r < 8; ++r) { acc0[r] = 0.f; acc1[r] = 0.f; }
            #pragma unroll 4
            for (int kc = 0; kc < DIN; kc += 4) {
                float4 w0 = *(const float4*)&sWT[c0 * DIN + (kc ^ swz0)];
                float4 w1 = *(const float4*)&sWT[c1 * DIN + (kc ^ swz1)];
                #pragma unroll
                for (int r = 0; r < 8; ++r) {
                    float4 a = *(const float4*)&sf[rg * 8 + r][kc];
                    acc0[r] += a.x * w0.x; acc0[r] += a.y * w0.y;
                    acc0[r] += a.z * w0.z; acc0[r] += a.w * w0.w;
                    acc1[r] += a.x * w1.x; acc1[r] += a.y * w1.y;
                    acc1[r] += a.z * w1.z; acc1[r] += a.w * w1.w;
                }
            }
            #pragma unroll
            for (int r = 0; r < 8; ++r) {
                int n = n0 + rg * 8 + r;
                if (n < NN) {
                    unsigned pk = (unsigned)f2bf(acc0[r]) | ((unsigned)f2bf(acc1[r]) << 16);
                    t1b[(size_t)n * 50 + j] = pk;
                }
            }
        }
    }
}

// ---------------- agg1: list-walk gather-mean + bias + relu -> packed bf16 h1b ----------------
// wave per node (8 waves/block), lane l<50 handles channels 2l,2l+1.
__global__ __launch_bounds__(512) void k_agg1(const unsigned* __restrict__ t1b,
                                              const int* __restrict__ head,
                                              const int* __restrict__ next,
                                              const int* __restrict__ srce,
                                              const float* __restrict__ b1,
                                              unsigned* __restrict__ h1b) {
    const int tid = threadIdx.x;
    const int w = tid >> 6, l = tid & 63;
    const int n = blockIdx.x * 8 + w;
    if (n >= NN || l >= 50) return;
    float acc0 = 0.f, acc1 = 0.f;
    int deg = 0;
    int e = head[n];
    while (e >= 0) {
        int en = next[e];                 // chain load issues early
        int s = srce[e];
        unsigned u = t1b[(size_t)s * 50 + l];
        acc0 += bf_lo(u); acc1 += bf_hi(u);
        ++deg;
        e = en;
    }
    float d = (float)(deg > 0 ? deg : 1);
    float v0 = fmaxf(acc0 / d + b1[2 * l], 0.f);
    float v1 = fmaxf(acc1 / d + b1[2 * l + 1], 0.f);
    h1b[(size_t)n * 50 + l] = (unsigned)f2bf(v0) | ((unsigned)f2bf(v1) << 16);
}

// ---------------- GCN layer 2 GEMM: t2 = h1 @ gc2_W ----------------
__global__ void k_gemm2(const unsigned* __restrict__ h1b, const float* __restrict__ W,
                        float* __restrict__ t2) {
    __shared__ float sW[C1 * C2];       // 8 KB
    __shared__ float sr[16][C1];        // 6.4 KB
    for (int idx = threadIdx.x; idx < C1 * C2; idx += 320) sW[idx] = W[idx];
    int ln = threadIdx.x / C2, j = threadIdx.x % C2;   // ln<16
    int n0 = blockIdx.x * 16;
    for (int idx = threadIdx.x; idx < 16 * 50; idx += 320) {
        int r = idx / 50, c = idx % 50;
        int n = n0 + r;
        unsigned u = (n < NN) ? h1b[(size_t)n * 50 + c] : 0u;
        sr[r][2 * c] = bf_lo(u);
        sr[r][2 * c + 1] = bf_hi(u);
    }
    __syncthreads();
    int n = n0 + ln;
    if (n < NN && ln < 16) {
        float acc = 0.f;
        #pragma unroll 4
        for (int k = 0; k < C1; ++k) acc += sr[ln][k] * sW[k * C2 + j];
        t2[(size_t)n * C2 + j] = acc;
    }
}

// ---------------- agg2 (list-walk mean+bias+relu) + graph pool (atomic) ----------------
// wave per node (8 waves/block), lane c<20 active.
__global__ __launch_bounds__(512) void k_agg2p(const float* __restrict__ t2,
                                               const int* __restrict__ head,
                                               const int* __restrict__ next,
                                               const int* __restrict__ srce,
                                               const float* __restrict__ bias,
                                               const int* __restrict__ gid,
                                               float* __restrict__ hgs) {
    const int tid = threadIdx.x;
    const int w = tid >> 6, c = tid & 63;
    const int n = blockIdx.x * 8 + w;
    if (n >= NN || c >= C2) return;
    float acc = 0.f;
    int deg = 0;
    int e = head[n];
    while (e >= 0) {
        int en = next[e];
        int s = srce[e];
        acc += t2[(size_t)s * C2 + c];
        ++deg;
        e = en;
    }
    float d = (float)(deg > 0 ? deg : 1);
    float v = fmaxf(acc / d + bias[c], 0.f);
    atomicAdd(&hgs[gid[n] * C2 + c], v);
}

// ---------------- fused per-graph tail: hg div (bsearch cnt) + attn head + d1ext prep ----------------
__global__ void k_headp(const float* __restrict__ hgs, const int* __restrict__ gid,
                        const float* __restrict__ desc2d,
                        const float* __restrict__ pgW, const float* __restrict__ pgb,
                        const float* __restrict__ p2W, const float* __restrict__ p2b,
                        const float* __restrict__ W2,
                        float* __restrict__ hg, float* __restrict__ d1ext) {
    __shared__ float shg[C2];
    __shared__ float sg[DHH];
    __shared__ float sa;
    int b = blockIdx.x, j = threadIdx.x;   // 64 threads
    // per-graph node count via binary search on sorted gid (uniform across threads)
    int lo = 0, hi = NN;
    while (lo < hi) { int m = (lo + hi) >> 1; if (gid[m] < b) lo = m + 1; else hi = m; }
    int lo2 = lo, hi2 = NN;
    while (lo2 < hi2) { int m = (lo2 + hi2) >> 1; if (gid[m] < b + 1) lo2 = m + 1; else hi2 = m; }
    float dcnt = (float)(lo2 - lo);
    if (dcnt < 1.f) dcnt = 1.f;
    if (j < C2) {
        float v = hgs[b * C2 + j] / dcnt;
        hg[b * C2 + j] = v;
        shg[j] = v;
    }
    __syncthreads();
    float hgj = pgb[j];
    #pragma unroll
    for (int k = 0; k < C2; ++k) hgj += shg[k] * pgW[k * DHH + j];
    float hdj = p2b[j];
    #pragma unroll 4
    for (int k = 0; k < DD2; ++k) hdj += desc2d[b * DD2 + k] * p2W[k * DHH + j];
    sg[j] = hgj;
    __syncthreads();
    float tj = 0.f;
    #pragma unroll 4
    for (int k = 0; k < DHH; ++k) tj += sg[k] * W2[k * DHH + j];
    float v = tj * hdj;
    #pragma unroll
    for (int off = 32; off; off >>= 1) v += __shfl_xor(v, off, 64);
    if (j == 0) sa = 1.f / (1.f + expf(-v));
    __syncthreads();
    float a = sa;
    for (int k = j; k < KDP; k += 64) {
        float vv = (k < DD2) ? a * desc2d[b * DD2 + k] : (k == DD2 ? 1.f : 0.f);
        d1ext[b * KDP + k] = vv;
    }
}

// ---------------- fc1 via rank-1 factorization ----------------
__global__ __launch_bounds__(256, 2) void k_fc1(const float* __restrict__ d1ext,
                                                const float* __restrict__ W1,
                                                float* __restrict__ U) {
    __shared__ float S[64][KDP];
    const int i = blockIdx.y;
    const int bt = blockIdx.x >> 1;
    const int half = blockIdx.x & 1;
    const int tid = threadIdx.x;
    const int c = tid & 31;
    const int rg = tid >> 5;

    {
        const float4* srcp = (const float4*)(d1ext + (size_t)bt * 64 * KDP);
        float4* dstp = (float4*)&S[0][0];
        for (int idx = tid; idx < 64 * (KDP / 4); idx += 256) dstp[idx] = srcp[idx];
    }
    __syncthreads();

    float acc[8][2];
    #pragma unroll
    for (int r = 0; r < 8; ++r) { acc[r][0] = 0.f; acc[r][1] = 0.f; }

    const float* Wb = W1 + (size_t)i * (KD * HH1) + half * 64 + c;
    for (int k = 0; k < 200; k += 4) {
        const float* Wk = Wb + (size_t)k * HH1;
        float w0[2], w1[2], w2[2], w3[2];
        #pragma unroll
        for (int m = 0; m < 2; ++m) {
            w0[m] = Wk[32 * m];
            w1[m] = Wk[HH1 + 32 * m];
            w2[m] = Wk[2 * HH1 + 32 * m];
            w3[m] = Wk[3 * HH1 + 32 * m];
        }
        #pragma unroll
        for (int r = 0; r < 8; ++r) {
            float4 a4 = *(const float4*)&S[rg * 8 + r][k];
            #pragma unroll
            for (int m = 0; m < 2; ++m)
                acc[r][m] += a4.x * w0[m] + a4.y * w1[m] + a4.z * w2[m] + a4.w * w3[m];
        }
    }
    {
        const float* Wk = Wb + (size_t)200 * HH1;
        float wl0 = Wk[0], wl1 = Wk[32];
        #pragma unroll
        for (int r = 0; r < 8; ++r) {
            float av = S[rg * 8 + r][200];
            acc[r][0] += av * wl0;
            acc[r][1] += av * wl1;
        }
    }
    #pragma unroll
    for (int r = 0; r < 8; ++r) {
        int b = bt * 64 + rg * 8 + r;
        float* Ur = U + (size_t)b * NU + i * HH1 + half * 64 + c;
        Ur[0] = acc[r][0];
        Ur[32] = acc[r][1];
    }
}

__global__ void k_fc1b(const float* __restrict__ U, const float* __restrict__ hg,
                       float* __restrict__ o1) {
    int idx = blockIdx.x * 256 + threadIdx.x;   // 65536
    int b = idx >> 7, j = idx & 127;
    const float* Ub = U + (size_t)b * NU + j;
    const float* hgb = hg + b * C2;
    float acc = Ub[20 * HH1];
    #pragma unroll
    for (int i = 0; i < 20; ++i) acc += hgb[i] * Ub[i * HH1];
    o1[idx] = acc;
}

// ---------------- batch-norm stats ----------------
__global__ void k_bnstats(const float* __restrict__ x, float* __restrict__ stats,
                          int ncols, int nrows) {
    __shared__ float sh[1024], sh2[1024];
    const int tid = threadIdx.x;
    const int j = tid % ncols;
    const int r = tid / ncols;
    const int R = 1024 / ncols;
    float s = 0.f, s2 = 0.f;
    for (int b = r; b < nrows; b += R) {
        float v = x[b * ncols + j];
        s += v; s2 += v * v;
    }
    sh[tid] = s; sh2[tid] = s2;
    __syncthreads();
    if (r == 0) {
        for (int q = 1; q < R; ++q) { s += sh[q * ncols + j]; s2 += sh2[q * ncols + j]; }
        float mu = s / nrows;
        float var = s2 / nrows - mu * mu;
        stats[j] = mu;
        stats[ncols + j] = rsqrtf(var + 1e-5f);
    }
}

// ---------------- fc2 (bn1 + relu fused) ----------------
__global__ void k_fc2(const float* __restrict__ o1, const float* __restrict__ st1,
                      const float* __restrict__ g, const float* __restrict__ beta,
                      const float* __restrict__ W, float* __restrict__ o2) {
    __shared__ float r[HH1];
    __shared__ float part[4][HH2];
    int b = blockIdx.x;
    int tid = threadIdx.x;   // 128
    float v = o1[b * HH1 + tid];
    float nv = (v - st1[tid]) * st1[HH1 + tid] * g[tid] + beta[tid];
    r[tid] = fmaxf(nv, 0.f);
    __syncthreads();
    int m = tid & 31, p = tid >> 5;
    float acc = 0.f;
    #pragma unroll 4
    for (int j = p * 32; j < p * 32 + 32; ++j) acc += r[j] * W[j * HH2 + m];
    part[p][m] = acc;
    __syncthreads();
    if (tid < HH2) o2[b * HH2 + tid] = part[0][tid] + part[1][tid] + part[2][tid] + part[3][tid];
}

// ---------------- bn2 + relu + fc3 ----------------
__global__ void k_final(const float* __restrict__ o2, const float* __restrict__ st2,
                        const float* __restrict__ g, const float* __restrict__ beta,
                        const float* __restrict__ W3, const float* __restrict__ b3,
                        float* __restrict__ out) {
    int b = threadIdx.x;    // 512
    if (b < NB) {
        float acc = b3[0];
        #pragma unroll 4
        for (int m = 0; m < HH2; ++m) {
            float v = o2[b * HH2 + m];
            float nv = (v - st2[m]) * st2[HH2 + m] * g[m] + beta[m];
            acc += fmaxf(nv, 0.f) * W3[m];
        }
        out[b] = acc;
    }
}

extern "C" void kernel_launch(void* const* d_in, const int* in_sizes, int n_in,
                              void* d_out, int out_size, void* d_ws, size_t ws_size,
                              hipStream_t stream) {
    const float* feat   = (const float*)d_in[0];
    const float* desc2d = (const float*)d_in[1];
    const float* gc1W = (const float*)d_in[3];
    const float* gc1b = (const float*)d_in[4];
    const float* gc2W = (const float*)d_in[5];
    const float* gc2b = (const float*)d_in[6];
    const float* pgW  = (const float*)d_in[7];
    const float* pgb  = (const float*)d_in[8];
    const float* p2W  = (const float*)d_in[9];
    const float* p2b  = (const float*)d_in[10];
    const float* W2   = (const float*)d_in[11];
    const float* fc1W = (const float*)d_in[12];
    const float* fc2W = (const float*)d_in[14];
    const float* fc3W = (const float*)d_in[16];
    const float* fc3b = (const float*)d_in[17];
    const float* bn1g = (const float*)d_in[18];
    const float* bn1b = (const float*)d_in[19];
    const float* bn2g = (const float*)d_in[20];
    const float* bn2b = (const float*)d_in[21];
    const int* src = (const int*)d_in[22];
    const int* dst = (const int*)d_in[23];
    const int* gid = (const int*)d_in[24];
    float* out = (float*)d_out;

    char* ws = (char*)d_ws;
    size_t off = 0;
    auto alloc = [&](size_t nb) {
        void* p = ws + off;
        off = (off + nb + 255) & ~(size_t)255;
        return p;
    };
    unsigned* t1b = (unsigned*)alloc((size_t)NN * 50 * 4);   // 10 MB packed bf16
    unsigned* h1b = (unsigned*)alloc((size_t)NN * 50 * 4);   // 10 MB packed bf16
    float* t2    = (float*)alloc((size_t)NN * C2 * 4);       // 4 MB
    int* head    = (int*)alloc((size_t)NN * 4);
    int* nxt     = (int*)alloc((size_t)NE * 4);
    float* hgs   = (float*)alloc((size_t)NB * C2 * 4);
    float* hg    = (float*)alloc((size_t)NB * C2 * 4);
    float* o1    = (float*)alloc((size_t)NB * HH1 * 4);
    float* st1   = (float*)alloc(2 * HH1 * 4);
    float* o2    = (float*)alloc((size_t)NB * HH2 * 4);
    float* st2   = (float*)alloc(2 * HH2 * 4);
    // fc1 scratch aliases t1b (dead after k_agg1)
    float* U     = (float*)t1b;                              // 5.5 MB < 10 MB
    float* d1ext = U + (size_t)NB * NU;

    hipMemsetAsync(head, 0xFF, (size_t)NN * 4, stream);      // head = -1
    hipMemsetAsync(hgs, 0, (size_t)NB * C2 * 4, stream);

    k_build<<<(NE + 255) / 256, 256, 0, stream>>>(dst, head, nxt);

    k_gemm1<<<512, 256, 0, stream>>>(feat, gc1W, t1b);
    k_agg1<<<(NN + 7) / 8, 512, 0, stream>>>(t1b, head, nxt, src, gc1b, h1b);
    k_gemm2<<<(NN + 15) / 16, 320, 0, stream>>>(h1b, gc2W, t2);
    k_agg2p<<<(NN + 7) / 8, 512, 0, stream>>>(t2, head, nxt, src, gc2b, gid, hgs);

    k_headp<<<NB, 64, 0, stream>>>(hgs, gid, desc2d, pgW, pgb, p2W, p2b, W2, hg, d1ext);

    dim3 g1(16, 21);
    k_fc1<<<g1, 256, 0, stream>>>(d1ext, fc1W, U);
    k_fc1b<<<NB * HH1 / 256, 256, 0, stream>>>(U, hg, o1);

    k_bnstats<<<1, 1024, 0, stream>>>(o1, st1, HH1, NB);
    k_fc2<<<NB, 128, 0, stream>>>(o1, st1, bn1g, bn1b, fc2W, o2);
    k_bnstats<<<1, 1024, 0, stream>>>(o2, st2, HH2, NB);
    k_final<<<1, 512, 0, stream>>>(o2, st2, bn2g, bn2b, fc3W, fc3b, out);
}

// Round 9
// 267.850 us; speedup vs baseline: 1.3609x; 1.3609x over previous
//
#include <hip/hip_runtime.h>

#define NN 50000
#define NE 800000
#define NB 512
#define DIN 128
#define DD2 200
#define C1 100
#define C2 20
#define DHH 64
#define HH1 128
#define HH2 32
#define KD 201      // fusion inner dim per i (200 + 1)
#define KDP 204     // padded row stride for d1ext
#define NU 2688     // 21 * 128
#define SCB 196     // scan blocks: ceil(50000/256)

__device__ __forceinline__ unsigned short f2bf(float x) {
    unsigned u = __float_as_uint(x);
    unsigned r = (u + 0x7fffu + ((u >> 16) & 1u)) >> 16;   // RNE
    return (unsigned short)r;
}
__device__ __forceinline__ float bf_lo(unsigned u) { return __uint_as_float(u << 16); }
__device__ __forceinline__ float bf_hi(unsigned u) { return __uint_as_float(u & 0xffff0000u); }

// ---------------- CSR build (2 passes, one atomic pass) ----------------
// pass 1: pos[e] = slot of edge e within its dst bucket; cnt ends as per-node degree.
__global__ void k_fillpos(const int* __restrict__ dst, int* __restrict__ cnt,
                          int* __restrict__ pos) {
    int e = blockIdx.x * 256 + threadIdx.x;
    if (e < NE) pos[e] = atomicAdd(&cnt[dst[e]], 1);
}

__global__ void k_scan1(const int* __restrict__ cnt, int* __restrict__ row_ptr,
                        int* __restrict__ bsum) {
    __shared__ int wsum[4];
    const int tid = threadIdx.x;          // 256
    const int lane = tid & 63, wid = tid >> 6;
    int i = blockIdx.x * 256 + tid;
    int v = (i < NN) ? cnt[i] : 0;
    int x = v;
    #pragma unroll
    for (int d = 1; d < 64; d <<= 1) {
        int t = __shfl_up(x, d, 64);
        if (lane >= d) x += t;
    }
    if (lane == 63) wsum[wid] = x;
    __syncthreads();
    int wpref = 0;
    #pragma unroll
    for (int w = 0; w < 4; ++w) if (w < wid) wpref += wsum[w];
    if (i < NN) row_ptr[i] = wpref + x - v;
    if (tid == 255) bsum[blockIdx.x] = wpref + x;
}

__global__ void k_scan2(int* __restrict__ bsum, int* __restrict__ row_ptr) {
    __shared__ int wsum[4];
    const int tid = threadIdx.x;
    const int lane = tid & 63, wid = tid >> 6;
    int v = (tid < SCB) ? bsum[tid] : 0;
    int x = v;
    #pragma unroll
    for (int d = 1; d < 64; d <<= 1) {
        int t = __shfl_up(x, d, 64);
        if (lane >= d) x += t;
    }
    if (lane == 63) wsum[wid] = x;
    __syncthreads();
    int wpref = 0;
    #pragma unroll
    for (int w = 0; w < 4; ++w) if (w < wid) wpref += wsum[w];
    if (tid < SCB) bsum[tid] = wpref + x - v;
    if (tid == 255) row_ptr[NN] = wpref + x;
}

__global__ void k_scan3(int* __restrict__ row_ptr, const int* __restrict__ bsum) {
    int i = blockIdx.x * 256 + threadIdx.x;
    if (i < NN) row_ptr[i] += bsum[blockIdx.x];
}

// pass 2: scatter src into elist — no atomics.
__global__ void k_scatter(const int* __restrict__ src, const int* __restrict__ dst,
                          const int* __restrict__ row_ptr, const int* __restrict__ pos,
                          int* __restrict__ elist) {
    int e = blockIdx.x * 256 + threadIdx.x;
    if (e < NE) elist[row_ptr[dst[e]] + pos[e]] = src[e];
}

// ---------------- GCN layer 1 GEMM ----------------
// t1b[n][j] = packed bf16 pair (channels 2j, 2j+1) of feat@gc1_W
__global__ __launch_bounds__(256, 2) void k_gemm1(const float* __restrict__ feat,
                                                  const float* __restrict__ W,
                                                  unsigned* __restrict__ t1b) {
    __shared__ float sWT[C1 * DIN];      // sWT[col*128 + (k ^ ((col&7)<<2))]
    __shared__ float sf[32][DIN + 4];
    const int tid = threadIdx.x;
    for (int idx = tid; idx < DIN * C1; idx += 256) {
        int k = idx / C1, col = idx % C1;
        sWT[col * DIN + (k ^ ((col & 7) << 2))] = W[idx];
    }
    const int j = tid & 63;              // active j<50: cols 2j, 2j+1
    const int rg = tid >> 6;             // 0..3
    const bool act = j < 50;
    const int c0 = 2 * j, c1 = 2 * j + 1;
    const int swz0 = (c0 & 7) << 2, swz1 = (c1 & 7) << 2;

    for (int n0 = blockIdx.x * 32; n0 < NN; n0 += gridDim.x * 32) {
        __syncthreads();
        {
            int r = tid >> 3, so = (tid & 7) * 16;
            int n = n0 + r;
            float4* dstp = (float4*)&sf[r][so];
            if (n < NN) {
                const float4* srcp = (const float4*)(feat + (size_t)n * DIN + so);
                dstp[0] = srcp[0]; dstp[1] = srcp[1]; dstp[2] = srcp[2]; dstp[3] = srcp[3];
            } else {
                float4 z = {0.f, 0.f, 0.f, 0.f};
                dstp[0] = z; dstp[1] = z; dstp[2] = z; dstp[3] = z;
            }
        }
        __syncthreads();
        if (act) {
            float acc0[8], acc1[8];
            #pragma unroll
            for (int r = 0; r < 8; ++r) { acc0[r] = 0.f; acc1[r] = 0.f; }
            #pragma unroll 4
            for (int kc = 0; kc < DIN; kc += 4) {
                float4 w0 = *(const float4*)&sWT[c0 * DIN + (kc ^ swz0)];
                float4 w1 = *(const float4*)&sWT[c1 * DIN + (kc ^ swz1)];
                #pragma unroll
                for (int r = 0; r < 8; ++r) {
                    float4 a = *(const float4*)&sf[rg * 8 + r][kc];
                    acc0[r] += a.x * w0.x; acc0[r] += a.y * w0.y;
                    acc0[r] += a.z * w0.z; acc0[r] += a.w * w0.w;
                    acc1[r] += a.x * w1.x; acc1[r] += a.y * w1.y;
                    acc1[r] += a.z * w1.z; acc1[r] += a.w * w1.w;
                }
            }
            #pragma unroll
            for (int r = 0; r < 8; ++r) {
                int n = n0 + rg * 8 + r;
                if (n < NN) {
                    unsigned pk = (unsigned)f2bf(acc0[r]) | ((unsigned)f2bf(acc1[r]) << 16);
                    t1b[(size_t)n * 50 + j] = pk;
                }
            }
        }
    }
}

// ---------------- agg1: CSR gather-mean + bias + relu -> packed bf16 h1b ----------------
// wave per node, lane l<50 handles channels 2l,2l+1; 8-deep load batches.
__global__ __launch_bounds__(256) void k_agg1(const unsigned* __restrict__ t1b,
                                              const int* __restrict__ row_ptr,
                                              const int* __restrict__ elist,
                                              const float* __restrict__ b1,
                                              unsigned* __restrict__ h1b) {
    const int tid = threadIdx.x;
    const int w = tid >> 6, l = tid & 63;
    const int n = blockIdx.x * 4 + w;
    if (n >= NN || l >= 50) return;
    const int e0 = row_ptr[n], e1 = row_ptr[n + 1];
    float acc0 = 0.f, acc1 = 0.f;
    int e = e0;
    for (; e + 7 < e1; e += 8) {
        int s0 = elist[e],     s1 = elist[e + 1], s2 = elist[e + 2], s3 = elist[e + 3];
        int s4 = elist[e + 4], s5 = elist[e + 5], s6 = elist[e + 6], s7 = elist[e + 7];
        unsigned u0 = t1b[(size_t)s0 * 50 + l];
        unsigned u1 = t1b[(size_t)s1 * 50 + l];
        unsigned u2 = t1b[(size_t)s2 * 50 + l];
        unsigned u3 = t1b[(size_t)s3 * 50 + l];
        unsigned u4 = t1b[(size_t)s4 * 50 + l];
        unsigned u5 = t1b[(size_t)s5 * 50 + l];
        unsigned u6 = t1b[(size_t)s6 * 50 + l];
        unsigned u7 = t1b[(size_t)s7 * 50 + l];
        acc0 += bf_lo(u0); acc1 += bf_hi(u0);
        acc0 += bf_lo(u1); acc1 += bf_hi(u1);
        acc0 += bf_lo(u2); acc1 += bf_hi(u2);
        acc0 += bf_lo(u3); acc1 += bf_hi(u3);
        acc0 += bf_lo(u4); acc1 += bf_hi(u4);
        acc0 += bf_lo(u5); acc1 += bf_hi(u5);
        acc0 += bf_lo(u6); acc1 += bf_hi(u6);
        acc0 += bf_lo(u7); acc1 += bf_hi(u7);
    }
    for (; e + 3 < e1; e += 4) {
        int s0 = elist[e], s1 = elist[e + 1], s2 = elist[e + 2], s3 = elist[e + 3];
        unsigned u0 = t1b[(size_t)s0 * 50 + l];
        unsigned u1 = t1b[(size_t)s1 * 50 + l];
        unsigned u2 = t1b[(size_t)s2 * 50 + l];
        unsigned u3 = t1b[(size_t)s3 * 50 + l];
        acc0 += bf_lo(u0); acc1 += bf_hi(u0);
        acc0 += bf_lo(u1); acc1 += bf_hi(u1);
        acc0 += bf_lo(u2); acc1 += bf_hi(u2);
        acc0 += bf_lo(u3); acc1 += bf_hi(u3);
    }
    for (; e < e1; ++e) {
        unsigned u = t1b[(size_t)elist[e] * 50 + l];
        acc0 += bf_lo(u); acc1 += bf_hi(u);
    }
    int deg = e1 - e0;
    float d = (float)(deg > 0 ? deg : 1);
    float v0 = fmaxf(acc0 / d + b1[2 * l], 0.f);
    float v1 = fmaxf(acc1 / d + b1[2 * l + 1], 0.f);
    h1b[(size_t)n * 50 + l] = (unsigned)f2bf(v0) | ((unsigned)f2bf(v1) << 16);
}

// ---------------- GCN layer 2 GEMM: t2 = h1 @ gc2_W ----------------
__global__ void k_gemm2(const unsigned* __restrict__ h1b, const float* __restrict__ W,
                        float* __restrict__ t2) {
    __shared__ float sW[C1 * C2];       // 8 KB
    __shared__ float sr[16][C1];        // 6.4 KB
    for (int idx = threadIdx.x; idx < C1 * C2; idx += 320) sW[idx] = W[idx];
    int ln = threadIdx.x / C2, j = threadIdx.x % C2;   // ln<16
    int n0 = blockIdx.x * 16;
    for (int idx = threadIdx.x; idx < 16 * 50; idx += 320) {
        int r = idx / 50, c = idx % 50;
        int n = n0 + r;
        unsigned u = (n < NN) ? h1b[(size_t)n * 50 + c] : 0u;
        sr[r][2 * c] = bf_lo(u);
        sr[r][2 * c + 1] = bf_hi(u);
    }
    __syncthreads();
    int n = n0 + ln;
    if (n < NN && ln < 16) {
        float acc = 0.f;
        #pragma unroll 4
        for (int k = 0; k < C1; ++k) acc += sr[ln][k] * sW[k * C2 + j];
        t2[(size_t)n * C2 + j] = acc;
    }
}

// ---------------- fused: agg2 (mean+bias+relu) + graph pool (atomic) ----------------
__global__ void k_agg2p(const float* __restrict__ t2, const int* __restrict__ row_ptr,
                        const int* __restrict__ elist, const float* __restrict__ bias,
                        const int* __restrict__ gid, float* __restrict__ hgs) {
    int ln = threadIdx.x / C2, c = threadIdx.x % C2;
    if (ln >= 12) return;
    int n = blockIdx.x * 12 + ln;
    if (n >= NN) return;
    int e0 = row_ptr[n], e1 = row_ptr[n + 1];
    float acc = 0.f;
    int e = e0;
    for (; e + 1 < e1; e += 2) {
        int s0 = elist[e], s1 = elist[e + 1];
        acc += t2[(size_t)s0 * C2 + c];
        acc += t2[(size_t)s1 * C2 + c];
    }
    for (; e < e1; ++e) acc += t2[(size_t)elist[e] * C2 + c];
    int deg = e1 - e0;
    float d = (float)(deg > 0 ? deg : 1);
    float v = acc / d + bias[c];
    v = v > 0.f ? v : 0.f;
    atomicAdd(&hgs[gid[n] * C2 + c], v);
}

// ---------------- fused per-graph tail: hg div (bsearch cnt) + attn head + d1ext prep ----------------
__global__ void k_headp(const float* __restrict__ hgs, const int* __restrict__ gid,
                        const float* __restrict__ desc2d,
                        const float* __restrict__ pgW, const float* __restrict__ pgb,
                        const float* __restrict__ p2W, const float* __restrict__ p2b,
                        const float* __restrict__ W2,
                        float* __restrict__ hg, float* __restrict__ d1ext) {
    __shared__ float shg[C2];
    __shared__ float sg[DHH];
    __shared__ float sa;
    int b = blockIdx.x, j = threadIdx.x;   // 64 threads
    int lo = 0, hi = NN;
    while (lo < hi) { int m = (lo + hi) >> 1; if (gid[m] < b) lo = m + 1; else hi = m; }
    int lo2 = lo, hi2 = NN;
    while (lo2 < hi2) { int m = (lo2 + hi2) >> 1; if (gid[m] < b + 1) lo2 = m + 1; else hi2 = m; }
    float dcnt = (float)(lo2 - lo);
    if (dcnt < 1.f) dcnt = 1.f;
    if (j < C2) {
        float v = hgs[b * C2 + j] / dcnt;
        hg[b * C2 + j] = v;
        shg[j] = v;
    }
    __syncthreads();
    float hgj = pgb[j];
    #pragma unroll
    for (int k = 0; k < C2; ++k) hgj += shg[k] * pgW[k * DHH + j];
    float hdj = p2b[j];
    #pragma unroll 4
    for (int k = 0; k < DD2; ++k) hdj += desc2d[b * DD2 + k] * p2W[k * DHH + j];
    sg[j] = hgj;
    __syncthreads();
    float tj = 0.f;
    #pragma unroll 4
    for (int k = 0; k < DHH; ++k) tj += sg[k] * W2[k * DHH + j];
    float v = tj * hdj;
    #pragma unroll
    for (int off = 32; off; off >>= 1) v += __shfl_xor(v, off, 64);
    if (j == 0) sa = 1.f / (1.f + expf(-v));
    __syncthreads();
    float a = sa;
    for (int k = j; k < KDP; k += 64) {
        float vv = (k < DD2) ? a * desc2d[b * DD2 + k] : (k == DD2 ? 1.f : 0.f);
        d1ext[b * KDP + k] = vv;
    }
}

// ---------------- fc1 via rank-1 factorization ----------------
__global__ __launch_bounds__(256, 2) void k_fc1(const float* __restrict__ d1ext,
                                                const float* __restrict__ W1,
                                                float* __restrict__ U) {
    __shared__ float S[64][KDP];
    const int i = blockIdx.y;
    const int bt = blockIdx.x >> 1;
    const int half = blockIdx.x & 1;
    const int tid = threadIdx.x;
    const int c = tid & 31;
    const int rg = tid >> 5;

    {
        const float4* srcp = (const float4*)(d1ext + (size_t)bt * 64 * KDP);
        float4* dstp = (float4*)&S[0][0];
        for (int idx = tid; idx < 64 * (KDP / 4); idx += 256) dstp[idx] = srcp[idx];
    }
    __syncthreads();

    float acc[8][2];
    #pragma unroll
    for (int r = 0; r < 8; ++r) { acc[r][0] = 0.f; acc[r][1] = 0.f; }

    const float* Wb = W1 + (size_t)i * (KD * HH1) + half * 64 + c;
    for (int k = 0; k < 200; k += 4) {
        const float* Wk = Wb + (size_t)k * HH1;
        float w0[2], w1[2], w2[2], w3[2];
        #pragma unroll
        for (int m = 0; m < 2; ++m) {
            w0[m] = Wk[32 * m];
            w1[m] = Wk[HH1 + 32 * m];
            w2[m] = Wk[2 * HH1 + 32 * m];
            w3[m] = Wk[3 * HH1 + 32 * m];
        }
        #pragma unroll
        for (int r = 0; r < 8; ++r) {
            float4 a4 = *(const float4*)&S[rg * 8 + r][k];
            #pragma unroll
            for (int m = 0; m < 2; ++m)
                acc[r][m] += a4.x * w0[m] + a4.y * w1[m] + a4.z * w2[m] + a4.w * w3[m];
        }
    }
    {
        const float* Wk = Wb + (size_t)200 * HH1;
        float wl0 = Wk[0], wl1 = Wk[32];
        #pragma unroll
        for (int r = 0; r < 8; ++r) {
            float av = S[rg * 8 + r][200];
            acc[r][0] += av * wl0;
            acc[r][1] += av * wl1;
        }
    }
    #pragma unroll
    for (int r = 0; r < 8; ++r) {
        int b = bt * 64 + rg * 8 + r;
        float* Ur = U + (size_t)b * NU + i * HH1 + half * 64 + c;
        Ur[0] = acc[r][0];
        Ur[32] = acc[r][1];
    }
}

__global__ void k_fc1b(const float* __restrict__ U, const float* __restrict__ hg,
                       float* __restrict__ o1) {
    int idx = blockIdx.x * 256 + threadIdx.x;   // 65536
    int b = idx >> 7, j = idx & 127;
    const float* Ub = U + (size_t)b * NU + j;
    const float* hgb = hg + b * C2;
    float acc = Ub[20 * HH1];
    #pragma unroll
    for (int i = 0; i < 20; ++i) acc += hgb[i] * Ub[i * HH1];
    o1[idx] = acc;
}

// ---------------- batch-norm stats ----------------
__global__ void k_bnstats(const float* __restrict__ x, float* __restrict__ stats,
                          int ncols, int nrows) {
    __shared__ float sh[1024], sh2[1024];
    const int tid = threadIdx.x;
    const int j = tid % ncols;
    const int r = tid / ncols;
    const int R = 1024 / ncols;
    float s = 0.f, s2 = 0.f;
    for (int b = r; b < nrows; b += R) {
        float v = x[b * ncols + j];
        s += v; s2 += v * v;
    }
    sh[tid] = s; sh2[tid] = s2;
    __syncthreads();
    if (r == 0) {
        for (int q = 1; q < R; ++q) { s += sh[q * ncols + j]; s2 += sh2[q * ncols + j]; }
        float mu = s / nrows;
        float var = s2 / nrows - mu * mu;
        stats[j] = mu;
        stats[ncols + j] = rsqrtf(var + 1e-5f);
    }
}

// ---------------- fc2 (bn1 + relu fused) ----------------
__global__ void k_fc2(const float* __restrict__ o1, const float* __restrict__ st1,
                      const float* __restrict__ g, const float* __restrict__ beta,
                      const float* __restrict__ W, float* __restrict__ o2) {
    __shared__ float r[HH1];
    __shared__ float part[4][HH2];
    int b = blockIdx.x;
    int tid = threadIdx.x;   // 128
    float v = o1[b * HH1 + tid];
    float nv = (v - st1[tid]) * st1[HH1 + tid] * g[tid] + beta[tid];
    r[tid] = fmaxf(nv, 0.f);
    __syncthreads();
    int m = tid & 31, p = tid >> 5;
    float acc = 0.f;
    #pragma unroll 4
    for (int j = p * 32; j < p * 32 + 32; ++j) acc += r[j] * W[j * HH2 + m];
    part[p][m] = acc;
    __syncthreads();
    if (tid < HH2) o2[b * HH2 + tid] = part[0][tid] + part[1][tid] + part[2][tid] + part[3][tid];
}

// ---------------- bn2 + relu + fc3 ----------------
__global__ void k_final(const float* __restrict__ o2, const float* __restrict__ st2,
                        const float* __restrict__ g, const float* __restrict__ beta,
                        const float* __restrict__ W3, const float* __restrict__ b3,
                        float* __restrict__ out) {
    int b = threadIdx.x;    // 512
    if (b < NB) {
        float acc = b3[0];
        #pragma unroll 4
        for (int m = 0; m < HH2; ++m) {
            float v = o2[b * HH2 + m];
            float nv = (v - st2[m]) * st2[HH2 + m] * g[m] + beta[m];
            acc += fmaxf(nv, 0.f) * W3[m];
        }
        out[b] = acc;
    }
}

extern "C" void kernel_launch(void* const* d_in, const int* in_sizes, int n_in,
                              void* d_out, int out_size, void* d_ws, size_t ws_size,
                              hipStream_t stream) {
    const float* feat   = (const float*)d_in[0];
    const float* desc2d = (const float*)d_in[1];
    const float* gc1W = (const float*)d_in[3];
    const float* gc1b = (const float*)d_in[4];
    const float* gc2W = (const float*)d_in[5];
    const float* gc2b = (const float*)d_in[6];
    const float* pgW  = (const float*)d_in[7];
    const float* pgb  = (const float*)d_in[8];
    const float* p2W  = (const float*)d_in[9];
    const float* p2b  = (const float*)d_in[10];
    const float* W2   = (const float*)d_in[11];
    const float* fc1W = (const float*)d_in[12];
    const float* fc2W = (const float*)d_in[14];
    const float* fc3W = (const float*)d_in[16];
    const float* fc3b = (const float*)d_in[17];
    const float* bn1g = (const float*)d_in[18];
    const float* bn1b = (const float*)d_in[19];
    const float* bn2g = (const float*)d_in[20];
    const float* bn2b = (const float*)d_in[21];
    const int* src = (const int*)d_in[22];
    const int* dst = (const int*)d_in[23];
    const int* gid = (const int*)d_in[24];
    float* out = (float*)d_out;

    char* ws = (char*)d_ws;
    size_t off = 0;
    auto alloc = [&](size_t nb) {
        void* p = ws + off;
        off = (off + nb + 255) & ~(size_t)255;
        return p;
    };
    unsigned* t1b = (unsigned*)alloc((size_t)NN * 50 * 4);   // 10 MB packed bf16
    unsigned* h1b = (unsigned*)alloc((size_t)NN * 50 * 4);   // 10 MB packed bf16
    float* t2    = (float*)alloc((size_t)NN * C2 * 4);       // 4 MB
    int* cnt_in  = (int*)alloc((size_t)NN * 4);
    int* row_ptr = (int*)alloc((size_t)(NN + 1) * 4);
    int* pos     = (int*)alloc((size_t)NE * 4);
    int* elist   = (int*)alloc((size_t)NE * 4);
    int* bsum    = (int*)alloc((size_t)256 * 4);
    float* hgs   = (float*)alloc((size_t)NB * C2 * 4);
    float* hg    = (float*)alloc((size_t)NB * C2 * 4);
    float* o1    = (float*)alloc((size_t)NB * HH1 * 4);
    float* st1   = (float*)alloc(2 * HH1 * 4);
    float* o2    = (float*)alloc((size_t)NB * HH2 * 4);
    float* st2   = (float*)alloc(2 * HH2 * 4);
    // fc1 scratch aliases t1b (dead after k_agg1)
    float* U     = (float*)t1b;                              // 5.5 MB < 10 MB
    float* d1ext = U + (size_t)NB * NU;

    hipMemsetAsync(cnt_in, 0, (size_t)NN * 4, stream);
    hipMemsetAsync(hgs, 0, (size_t)NB * C2 * 4, stream);

    k_fillpos<<<(NE + 255) / 256, 256, 0, stream>>>(dst, cnt_in, pos);
    k_scan1<<<SCB, 256, 0, stream>>>(cnt_in, row_ptr, bsum);
    k_scan2<<<1, 256, 0, stream>>>(bsum, row_ptr);
    k_scan3<<<SCB, 256, 0, stream>>>(row_ptr, bsum);
    k_scatter<<<(NE + 255) / 256, 256, 0, stream>>>(src, dst, row_ptr, pos, elist);

    k_gemm1<<<512, 256, 0, stream>>>(feat, gc1W, t1b);
    k_agg1<<<(NN + 3) / 4, 256, 0, stream>>>(t1b, row_ptr, elist, gc1b, h1b);
    k_gemm2<<<(NN + 15) / 16, 320, 0, stream>>>(h1b, gc2W, t2);
    k_agg2p<<<(NN + 11) / 12, 256, 0, stream>>>(t2, row_ptr, elist, gc2b, gid, hgs);

    k_headp<<<NB, 64, 0, stream>>>(hgs, gid, desc2d, pgW, pgb, p2W, p2b, W2, hg, d1ext);

    dim3 g1(16, 21);
    k_fc1<<<g1, 256, 0, stream>>>(d1ext, fc1W, U);
    k_fc1b<<<NB * HH1 / 256, 256, 0, stream>>>(U, hg, o1);

    k_bnstats<<<1, 1024, 0, stream>>>(o1, st1, HH1, NB);
    k_fc2<<<NB, 128, 0, stream>>>(o1, st1, bn1g, bn1b, fc2W, o2);
    k_bnstats<<<1, 1024, 0, stream>>>(o2, st2, HH2, NB);
    k_final<<<1, 512, 0, stream>>>(o2, st2, bn2g, bn2b, fc3W, fc3b, out);
}

// Round 10
// 245.824 us; speedup vs baseline: 1.4828x; 1.0896x over previous
//
#include <hip/hip_runtime.h>

#define NN 50000
#define NE 800000
#define NB 512
#define DIN 128
#define DD2 200
#define C1 100
#define C2 20
#define DHH 64
#define HH1 128
#define HH2 32
#define KD 201      // fusion inner dim per i (200 + 1)
#define KDP 204     // padded row stride for d1ext
#define NU 2688     // 21 * 128
#define SCB 196     // scan blocks: ceil(50000/256)
#define NCT 7       // col tiles of 16 covering 100 (112 padded)
#define NTILE 3125  // 50000 / 16 row tiles

typedef short sh8 __attribute__((ext_vector_type(8)));
typedef float f32x4 __attribute__((ext_vector_type(4)));

__device__ __forceinline__ unsigned short f2bf(float x) {
    unsigned u = __float_as_uint(x);
    unsigned r = (u + 0x7fffu + ((u >> 16) & 1u)) >> 16;   // RNE
    return (unsigned short)r;
}
__device__ __forceinline__ float bf_lo(unsigned u) { return __uint_as_float(u << 16); }
__device__ __forceinline__ float bf_hi(unsigned u) { return __uint_as_float(u & 0xffff0000u); }

// ---------------- CSR build (2 passes, one atomic pass) ----------------
__global__ void k_fillpos(const int* __restrict__ dst, int* __restrict__ cnt,
                          int* __restrict__ pos) {
    int e = blockIdx.x * 256 + threadIdx.x;
    if (e < NE) pos[e] = atomicAdd(&cnt[dst[e]], 1);
}

__global__ void k_scan1(const int* __restrict__ cnt, int* __restrict__ row_ptr,
                        int* __restrict__ bsum) {
    __shared__ int wsum[4];
    const int tid = threadIdx.x;          // 256
    const int lane = tid & 63, wid = tid >> 6;
    int i = blockIdx.x * 256 + tid;
    int v = (i < NN) ? cnt[i] : 0;
    int x = v;
    #pragma unroll
    for (int d = 1; d < 64; d <<= 1) {
        int t = __shfl_up(x, d, 64);
        if (lane >= d) x += t;
    }
    if (lane == 63) wsum[wid] = x;
    __syncthreads();
    int wpref = 0;
    #pragma unroll
    for (int w = 0; w < 4; ++w) if (w < wid) wpref += wsum[w];
    if (i < NN) row_ptr[i] = wpref + x - v;
    if (tid == 255) bsum[blockIdx.x] = wpref + x;
}

__global__ void k_scan2(int* __restrict__ bsum, int* __restrict__ row_ptr) {
    __shared__ int wsum[4];
    const int tid = threadIdx.x;
    const int lane = tid & 63, wid = tid >> 6;
    int v = (tid < SCB) ? bsum[tid] : 0;
    int x = v;
    #pragma unroll
    for (int d = 1; d < 64; d <<= 1) {
        int t = __shfl_up(x, d, 64);
        if (lane >= d) x += t;
    }
    if (lane == 63) wsum[wid] = x;
    __syncthreads();
    int wpref = 0;
    #pragma unroll
    for (int w = 0; w < 4; ++w) if (w < wid) wpref += wsum[w];
    if (tid < SCB) bsum[tid] = wpref + x - v;
    if (tid == 255) row_ptr[NN] = wpref + x;
}

__global__ void k_scan3(int* __restrict__ row_ptr, const int* __restrict__ bsum) {
    int i = blockIdx.x * 256 + threadIdx.x;
    if (i < NN) row_ptr[i] += bsum[blockIdx.x];
}

__global__ void k_scatter(const int* __restrict__ src, const int* __restrict__ dst,
                          const int* __restrict__ row_ptr, const int* __restrict__ pos,
                          int* __restrict__ elist) {
    int e = blockIdx.x * 256 + threadIdx.x;
    if (e < NE) elist[row_ptr[dst[e]] + pos[e]] = src[e];
}

// ---------------- pack gc1_W into MFMA B-fragments ----------------
// Bf slot idx = ct*256 + kc*64 + lane, 8 bf16 each:
//   Bf[idx][e] = W[kc*32 + (lane>>4)*8 + e][ct*16 + (lane&15)]  (0 if col>=100)
__global__ void k_packB(const float* __restrict__ W, unsigned short* __restrict__ Bf) {
    int idx = blockIdx.x * 256 + threadIdx.x;
    if (idx < NCT * 4 * 64) {
        int lane = idx & 63;
        int kc = (idx >> 6) & 3;
        int ct = idx >> 8;
        int col = ct * 16 + (lane & 15);
        int k0 = kc * 32 + (lane >> 4) * 8;
        unsigned short* outp = Bf + (size_t)idx * 8;
        #pragma unroll
        for (int e = 0; e < 8; ++e) {
            float v = (col < C1) ? W[(k0 + e) * C1 + col] : 0.f;
            outp[e] = f2bf(v);
        }
    }
}

// ---------------- GCN layer 1 GEMM via MFMA ----------------
// t1h[n][c] bf16 = (feat @ gc1_W)[n][c]; wave per 16-row tile, 7 col tiles live.
__global__ __launch_bounds__(256) void k_gemm1(const float* __restrict__ feat,
                                               const unsigned short* __restrict__ Bf,
                                               unsigned short* __restrict__ t1h) {
    __shared__ sh8 sB[NCT][4][64];       // 28 KB
    const int tid = threadIdx.x;
    {
        const uint4* srcp = (const uint4*)Bf;
        uint4* dstp = (uint4*)&sB[0][0][0];
        for (int i = tid; i < NCT * 4 * 64; i += 256) dstp[i] = srcp[i];
    }
    __syncthreads();
    const int w = tid >> 6, lane = tid & 63;
    const int ri = lane & 15;            // A row within tile / D col low
    const int kg = lane >> 4;            // 0..3
    for (int tile = blockIdx.x * 4 + w; tile < NTILE; tile += gridDim.x * 4) {
        const int n = tile * 16 + ri;
        f32x4 acc[NCT];
        #pragma unroll
        for (int ct = 0; ct < NCT; ++ct) acc[ct] = (f32x4){0.f, 0.f, 0.f, 0.f};
        #pragma unroll
        for (int kc = 0; kc < 4; ++kc) {
            const float* ap = feat + (size_t)n * DIN + kc * 32 + kg * 8;
            float4 a0 = *(const float4*)ap;
            float4 a1 = *(const float4*)(ap + 4);
            union { sh8 v; unsigned short u[8]; } af;
            af.u[0] = f2bf(a0.x); af.u[1] = f2bf(a0.y);
            af.u[2] = f2bf(a0.z); af.u[3] = f2bf(a0.w);
            af.u[4] = f2bf(a1.x); af.u[5] = f2bf(a1.y);
            af.u[6] = f2bf(a1.z); af.u[7] = f2bf(a1.w);
            #pragma unroll
            for (int ct = 0; ct < NCT; ++ct)
                acc[ct] = __builtin_amdgcn_mfma_f32_16x16x32_bf16(
                    af.v, sB[ct][kc][lane], acc[ct], 0, 0, 0);
        }
        // D: col = ct*16 + (lane&15), row = tile*16 + kg*4 + r
        const int rbase = tile * 16 + kg * 4;
        #pragma unroll
        for (int ct = 0; ct < NCT; ++ct) {
            int col = ct * 16 + ri;
            if (col < C1) {
                #pragma unroll
                for (int r = 0; r < 4; ++r)
                    t1h[(size_t)(rbase + r) * C1 + col] = f2bf(acc[ct][r]);
            }
        }
    }
}

// ---------------- agg1: CSR gather-mean + bias + relu -> packed bf16 h1b ----------------
__global__ __launch_bounds__(256) void k_agg1(const unsigned* __restrict__ t1b,
                                              const int* __restrict__ row_ptr,
                                              const int* __restrict__ elist,
                                              const float* __restrict__ b1,
                                              unsigned* __restrict__ h1b) {
    const int tid = threadIdx.x;
    const int w = tid >> 6, l = tid & 63;
    const int n = blockIdx.x * 4 + w;
    if (n >= NN || l >= 50) return;
    const int e0 = row_ptr[n], e1 = row_ptr[n + 1];
    float acc0 = 0.f, acc1 = 0.f;
    int e = e0;
    for (; e + 7 < e1; e += 8) {
        int s0 = elist[e],     s1 = elist[e + 1], s2 = elist[e + 2], s3 = elist[e + 3];
        int s4 = elist[e + 4], s5 = elist[e + 5], s6 = elist[e + 6], s7 = elist[e + 7];
        unsigned u0 = t1b[(size_t)s0 * 50 + l];
        unsigned u1 = t1b[(size_t)s1 * 50 + l];
        unsigned u2 = t1b[(size_t)s2 * 50 + l];
        unsigned u3 = t1b[(size_t)s3 * 50 + l];
        unsigned u4 = t1b[(size_t)s4 * 50 + l];
        unsigned u5 = t1b[(size_t)s5 * 50 + l];
        unsigned u6 = t1b[(size_t)s6 * 50 + l];
        unsigned u7 = t1b[(size_t)s7 * 50 + l];
        acc0 += bf_lo(u0); acc1 += bf_hi(u0);
        acc0 += bf_lo(u1); acc1 += bf_hi(u1);
        acc0 += bf_lo(u2); acc1 += bf_hi(u2);
        acc0 += bf_lo(u3); acc1 += bf_hi(u3);
        acc0 += bf_lo(u4); acc1 += bf_hi(u4);
        acc0 += bf_lo(u5); acc1 += bf_hi(u5);
        acc0 += bf_lo(u6); acc1 += bf_hi(u6);
        acc0 += bf_lo(u7); acc1 += bf_hi(u7);
    }
    for (; e + 3 < e1; e += 4) {
        int s0 = elist[e], s1 = elist[e + 1], s2 = elist[e + 2], s3 = elist[e + 3];
        unsigned u0 = t1b[(size_t)s0 * 50 + l];
        unsigned u1 = t1b[(size_t)s1 * 50 + l];
        unsigned u2 = t1b[(size_t)s2 * 50 + l];
        unsigned u3 = t1b[(size_t)s3 * 50 + l];
        acc0 += bf_lo(u0); acc1 += bf_hi(u0);
        acc0 += bf_lo(u1); acc1 += bf_hi(u1);
        acc0 += bf_lo(u2); acc1 += bf_hi(u2);
        acc0 += bf_lo(u3); acc1 += bf_hi(u3);
    }
    for (; e < e1; ++e) {
        unsigned u = t1b[(size_t)elist[e] * 50 + l];
        acc0 += bf_lo(u); acc1 += bf_hi(u);
    }
    int deg = e1 - e0;
    float d = (float)(deg > 0 ? deg : 1);
    float v0 = fmaxf(acc0 / d + b1[2 * l], 0.f);
    float v1 = fmaxf(acc1 / d + b1[2 * l + 1], 0.f);
    h1b[(size_t)n * 50 + l] = (unsigned)f2bf(v0) | ((unsigned)f2bf(v1) << 16);
}

// ---------------- GCN layer 2 GEMM: t2 = h1 @ gc2_W ----------------
__global__ void k_gemm2(const unsigned* __restrict__ h1b, const float* __restrict__ W,
                        float* __restrict__ t2) {
    __shared__ float sW[C1 * C2];       // 8 KB
    __shared__ float sr[16][C1];        // 6.4 KB
    for (int idx = threadIdx.x; idx < C1 * C2; idx += 320) sW[idx] = W[idx];
    int ln = threadIdx.x / C2, j = threadIdx.x % C2;   // ln<16
    int n0 = blockIdx.x * 16;
    for (int idx = threadIdx.x; idx < 16 * 50; idx += 320) {
        int r = idx / 50, c = idx % 50;
        int n = n0 + r;
        unsigned u = (n < NN) ? h1b[(size_t)n * 50 + c] : 0u;
        sr[r][2 * c] = bf_lo(u);
        sr[r][2 * c + 1] = bf_hi(u);
    }
    __syncthreads();
    int n = n0 + ln;
    if (n < NN && ln < 16) {
        float acc = 0.f;
        #pragma unroll 4
        for (int k = 0; k < C1; ++k) acc += sr[ln][k] * sW[k * C2 + j];
        t2[(size_t)n * C2 + j] = acc;
    }
}

// ---------------- fused: agg2 (mean+bias+relu) + graph pool (atomic) ----------------
__global__ void k_agg2p(const float* __restrict__ t2, const int* __restrict__ row_ptr,
                        const int* __restrict__ elist, const float* __restrict__ bias,
                        const int* __restrict__ gid, float* __restrict__ hgs) {
    int ln = threadIdx.x / C2, c = threadIdx.x % C2;
    if (ln >= 12) return;
    int n = blockIdx.x * 12 + ln;
    if (n >= NN) return;
    int e0 = row_ptr[n], e1 = row_ptr[n + 1];
    float acc = 0.f;
    int e = e0;
    for (; e + 1 < e1; e += 2) {
        int s0 = elist[e], s1 = elist[e + 1];
        acc += t2[(size_t)s0 * C2 + c];
        acc += t2[(size_t)s1 * C2 + c];
    }
    for (; e < e1; ++e) acc += t2[(size_t)elist[e] * C2 + c];
    int deg = e1 - e0;
    float d = (float)(deg > 0 ? deg : 1);
    float v = acc / d + bias[c];
    v = v > 0.f ? v : 0.f;
    atomicAdd(&hgs[gid[n] * C2 + c], v);
}

// ---------------- fused per-graph tail: hg div (bsearch cnt) + attn head + d1ext prep ----------------
__global__ void k_headp(const float* __restrict__ hgs, const int* __restrict__ gid,
                        const float* __restrict__ desc2d,
                        const float* __restrict__ pgW, const float* __restrict__ pgb,
                        const float* __restrict__ p2W, const float* __restrict__ p2b,
                        const float* __restrict__ W2,
                        float* __restrict__ hg, float* __restrict__ d1ext) {
    __shared__ float shg[C2];
    __shared__ float sg[DHH];
    __shared__ float sa;
    int b = blockIdx.x, j = threadIdx.x;   // 64 threads
    int lo = 0, hi = NN;
    while (lo < hi) { int m = (lo + hi) >> 1; if (gid[m] < b) lo = m + 1; else hi = m; }
    int lo2 = lo, hi2 = NN;
    while (lo2 < hi2) { int m = (lo2 + hi2) >> 1; if (gid[m] < b + 1) lo2 = m + 1; else hi2 = m; }
    float dcnt = (float)(lo2 - lo);
    if (dcnt < 1.f) dcnt = 1.f;
    if (j < C2) {
        float v = hgs[b * C2 + j] / dcnt;
        hg[b * C2 + j] = v;
        shg[j] = v;
    }
    __syncthreads();
    float hgj = pgb[j];
    #pragma unroll
    for (int k = 0; k < C2; ++k) hgj += shg[k] * pgW[k * DHH + j];
    float hdj = p2b[j];
    #pragma unroll 4
    for (int k = 0; k < DD2; ++k) hdj += desc2d[b * DD2 + k] * p2W[k * DHH + j];
    sg[j] = hgj;
    __syncthreads();
    float tj = 0.f;
    #pragma unroll 4
    for (int k = 0; k < DHH; ++k) tj += sg[k] * W2[k * DHH + j];
    float v = tj * hdj;
    #pragma unroll
    for (int off = 32; off; off >>= 1) v += __shfl_xor(v, off, 64);
    if (j == 0) sa = 1.f / (1.f + expf(-v));
    __syncthreads();
    float a = sa;
    for (int k = j; k < KDP; k += 64) {
        float vv = (k < DD2) ? a * desc2d[b * DD2 + k] : (k == DD2 ? 1.f : 0.f);
        d1ext[b * KDP + k] = vv;
    }
}

// ---------------- fc1 via rank-1 factorization ----------------
__global__ __launch_bounds__(256, 2) void k_fc1(const float* __restrict__ d1ext,
                                                const float* __restrict__ W1,
                                                float* __restrict__ U) {
    __shared__ float S[64][KDP];
    const int i = blockIdx.y;
    const int bt = blockIdx.x >> 1;
    const int half = blockIdx.x & 1;
    const int tid = threadIdx.x;
    const int c = tid & 31;
    const int rg = tid >> 5;

    {
        const float4* srcp = (const float4*)(d1ext + (size_t)bt * 64 * KDP);
        float4* dstp = (float4*)&S[0][0];
        for (int idx = tid; idx < 64 * (KDP / 4); idx += 256) dstp[idx] = srcp[idx];
    }
    __syncthreads();

    float acc[8][2];
    #pragma unroll
    for (int r = 0; r < 8; ++r) { acc[r][0] = 0.f; acc[r][1] = 0.f; }

    const float* Wb = W1 + (size_t)i * (KD * HH1) + half * 64 + c;
    for (int k = 0; k < 200; k += 4) {
        const float* Wk = Wb + (size_t)k * HH1;
        float w0[2], w1[2], w2[2], w3[2];
        #pragma unroll
        for (int m = 0; m < 2; ++m) {
            w0[m] = Wk[32 * m];
            w1[m] = Wk[HH1 + 32 * m];
            w2[m] = Wk[2 * HH1 + 32 * m];
            w3[m] = Wk[3 * HH1 + 32 * m];
        }
        #pragma unroll
        for (int r = 0; r < 8; ++r) {
            float4 a4 = *(const float4*)&S[rg * 8 + r][k];
            #pragma unroll
            for (int m = 0; m < 2; ++m)
                acc[r][m] += a4.x * w0[m] + a4.y * w1[m] + a4.z * w2[m] + a4.w * w3[m];
        }
    }
    {
        const float* Wk = Wb + (size_t)200 * HH1;
        float wl0 = Wk[0], wl1 = Wk[32];
        #pragma unroll
        for (int r = 0; r < 8; ++r) {
            float av = S[rg * 8 + r][200];
            acc[r][0] += av * wl0;
            acc[r][1] += av * wl1;
        }
    }
    #pragma unroll
    for (int r = 0; r < 8; ++r) {
        int b = bt * 64 + rg * 8 + r;
        float* Ur = U + (size_t)b * NU + i * HH1 + half * 64 + c;
        Ur[0] = acc[r][0];
        Ur[32] = acc[r][1];
    }
}

__global__ void k_fc1b(const float* __restrict__ U, const float* __restrict__ hg,
                       float* __restrict__ o1) {
    int idx = blockIdx.x * 256 + threadIdx.x;   // 65536
    int b = idx >> 7, j = idx & 127;
    const float* Ub = U + (size_t)b * NU + j;
    const float* hgb = hg + b * C2;
    float acc = Ub[20 * HH1];
    #pragma unroll
    for (int i = 0; i < 20; ++i) acc += hgb[i] * Ub[i * HH1];
    o1[idx] = acc;
}

// ---------------- batch-norm stats ----------------
__global__ void k_bnstats(const float* __restrict__ x, float* __restrict__ stats,
                          int ncols, int nrows) {
    __shared__ float sh[1024], sh2[1024];
    const int tid = threadIdx.x;
    const int j = tid % ncols;
    const int r = tid / ncols;
    const int R = 1024 / ncols;
    float s = 0.f, s2 = 0.f;
    for (int b = r; b < nrows; b += R) {
        float v = x[b * ncols + j];
        s += v; s2 += v * v;
    }
    sh[tid] = s; sh2[tid] = s2;
    __syncthreads();
    if (r == 0) {
        for (int q = 1; q < R; ++q) { s += sh[q * ncols + j]; s2 += sh2[q * ncols + j]; }
        float mu = s / nrows;
        float var = s2 / nrows - mu * mu;
        stats[j] = mu;
        stats[ncols + j] = rsqrtf(var + 1e-5f);
    }
}

// ---------------- fc2 (bn1 + relu fused) ----------------
__global__ void k_fc2(const float* __restrict__ o1, const float* __restrict__ st1,
                      const float* __restrict__ g, const float* __restrict__ beta,
                      const float* __restrict__ W, float* __restrict__ o2) {
    __shared__ float r[HH1];
    __shared__ float part[4][HH2];
    int b = blockIdx.x;
    int tid = threadIdx.x;   // 128
    float v = o1[b * HH1 + tid];
    float nv = (v - st1[tid]) * st1[HH1 + tid] * g[tid] + beta[tid];
    r[tid] = fmaxf(nv, 0.f);
    __syncthreads();
    int m = tid & 31, p = tid >> 5;
    float acc = 0.f;
    #pragma unroll 4
    for (int j = p * 32; j < p * 32 + 32; ++j) acc += r[j] * W[j * HH2 + m];
    part[p][m] = acc;
    __syncthreads();
    if (tid < HH2) o2[b * HH2 + tid] = part[0][tid] + part[1][tid] + part[2][tid] + part[3][tid];
}

// ---------------- bn2 + relu + fc3 ----------------
__global__ void k_final(const float* __restrict__ o2, const float* __restrict__ st2,
                        const float* __restrict__ g, const float* __restrict__ beta,
                        const float* __restrict__ W3, const float* __restrict__ b3,
                        float* __restrict__ out) {
    int b = threadIdx.x;    // 512
    if (b < NB) {
        float acc = b3[0];
        #pragma unroll 4
        for (int m = 0; m < HH2; ++m) {
            float v = o2[b * HH2 + m];
            float nv = (v - st2[m]) * st2[HH2 + m] * g[m] + beta[m];
            acc += fmaxf(nv, 0.f) * W3[m];
        }
        out[b] = acc;
    }
}

extern "C" void kernel_launch(void* const* d_in, const int* in_sizes, int n_in,
                              void* d_out, int out_size, void* d_ws, size_t ws_size,
                              hipStream_t stream) {
    const float* feat   = (const float*)d_in[0];
    const float* desc2d = (const float*)d_in[1];
    const float* gc1W = (const float*)d_in[3];
    const float* gc1b = (const float*)d_in[4];
    const float* gc2W = (const float*)d_in[5];
    const float* gc2b = (const float*)d_in[6];
    const float* pgW  = (const float*)d_in[7];
    const float* pgb  = (const float*)d_in[8];
    const float* p2W  = (const float*)d_in[9];
    const float* p2b  = (const float*)d_in[10];
    const float* W2   = (const float*)d_in[11];
    const float* fc1W = (const float*)d_in[12];
    const float* fc2W = (const float*)d_in[14];
    const float* fc3W = (const float*)d_in[16];
    const float* fc3b = (const float*)d_in[17];
    const float* bn1g = (const float*)d_in[18];
    const float* bn1b = (const float*)d_in[19];
    const float* bn2g = (const float*)d_in[20];
    const float* bn2b = (const float*)d_in[21];
    const int* src = (const int*)d_in[22];
    const int* dst = (const int*)d_in[23];
    const int* gid = (const int*)d_in[24];
    float* out = (float*)d_out;

    char* ws = (char*)d_ws;
    size_t off = 0;
    auto alloc = [&](size_t nb) {
        void* p = ws + off;
        off = (off + nb + 255) & ~(size_t)255;
        return p;
    };
    unsigned* t1b = (unsigned*)alloc((size_t)NN * 50 * 4);   // 10 MB packed bf16 (= [NN][100] bf16)
    unsigned* h1b = (unsigned*)alloc((size_t)NN * 50 * 4);   // 10 MB packed bf16
    float* t2    = (float*)alloc((size_t)NN * C2 * 4);       // 4 MB
    int* cnt_in  = (int*)alloc((size_t)NN * 4);
    int* row_ptr = (int*)alloc((size_t)(NN + 1) * 4);
    int* pos     = (int*)alloc((size_t)NE * 4);
    int* elist   = (int*)alloc((size_t)NE * 4);
    int* bsum    = (int*)alloc((size_t)256 * 4);
    unsigned short* Bf = (unsigned short*)alloc((size_t)NCT * 4 * 64 * 16);  // 28 KB
    float* hgs   = (float*)alloc((size_t)NB * C2 * 4);
    float* hg    = (float*)alloc((size_t)NB * C2 * 4);
    float* o1    = (float*)alloc((size_t)NB * HH1 * 4);
    float* st1   = (float*)alloc(2 * HH1 * 4);
    float* o2    = (float*)alloc((size_t)NB * HH2 * 4);
    float* st2   = (float*)alloc(2 * HH2 * 4);
    // fc1 scratch aliases t1b (dead after k_agg1)
    float* U     = (float*)t1b;                              // 5.5 MB < 10 MB
    float* d1ext = U + (size_t)NB * NU;

    hipMemsetAsync(cnt_in, 0, (size_t)NN * 4, stream);
    hipMemsetAsync(hgs, 0, (size_t)NB * C2 * 4, stream);

    k_packB<<<7, 256, 0, stream>>>(gc1W, Bf);
    k_fillpos<<<(NE + 255) / 256, 256, 0, stream>>>(dst, cnt_in, pos);
    k_scan1<<<SCB, 256, 0, stream>>>(cnt_in, row_ptr, bsum);
    k_scan2<<<1, 256, 0, stream>>>(bsum, row_ptr);
    k_scan3<<<SCB, 256, 0, stream>>>(row_ptr, bsum);
    k_scatter<<<(NE + 255) / 256, 256, 0, stream>>>(src, dst, row_ptr, pos, elist);

    k_gemm1<<<782, 256, 0, stream>>>(feat, Bf, (unsigned short*)t1b);
    k_agg1<<<(NN + 3) / 4, 256, 0, stream>>>(t1b, row_ptr, elist, gc1b, h1b);
    k_gemm2<<<(NN + 15) / 16, 320, 0, stream>>>(h1b, gc2W, t2);
    k_agg2p<<<(NN + 11) / 12, 256, 0, stream>>>(t2, row_ptr, elist, gc2b, gid, hgs);

    k_headp<<<NB, 64, 0, stream>>>(hgs, gid, desc2d, pgW, pgb, p2W, p2b, W2, hg, d1ext);

    dim3 g1(16, 21);
    k_fc1<<<g1, 256, 0, stream>>>(d1ext, fc1W, U);
    k_fc1b<<<NB * HH1 / 256, 256, 0, stream>>>(U, hg, o1);

    k_bnstats<<<1, 1024, 0, stream>>>(o1, st1, HH1, NB);
    k_fc2<<<NB, 128, 0, stream>>>(o1, st1, bn1g, bn1b, fc2W, o2);
    k_bnstats<<<1, 1024, 0, stream>>>(o2, st2, HH2, NB);
    k_final<<<1, 512, 0, stream>>>(o2, st2, bn2g, bn2b, fc3W, fc3b, out);
}

// Round 11
// 228.338 us; speedup vs baseline: 1.5964x; 1.0766x over previous
//
#include <hip/hip_runtime.h>

#define NN 50000
#define NE 800000
#define NB 512
#define DIN 128
#define DD2 200
#define C1 100
#define C2 20
#define DHH 64
#define HH1 128
#define HH2 32
#define KD 201      // fusion inner dim per i (200 + 1)
#define KDP 204     // padded row stride for d1ext
#define NU 2688     // 21 * 128
#define SCB 196     // scan blocks: ceil(50000/256)
#define NCT 7       // col tiles of 16 covering 100 (112 padded)
#define NTILE 3125  // 50000 / 16 row tiles
#define GB1 782     // gemm1 blocks in k_front
#define FPB 3125    // fillpos blocks in k_front

typedef short sh8 __attribute__((ext_vector_type(8)));
typedef float f32x4 __attribute__((ext_vector_type(4)));

__device__ __forceinline__ unsigned short f2bf(float x) {
    unsigned u = __float_as_uint(x);
    unsigned r = (u + 0x7fffu + ((u >> 16) & 1u)) >> 16;   // RNE
    return (unsigned short)r;
}
__device__ __forceinline__ float bf_lo(unsigned u) { return __uint_as_float(u << 16); }
__device__ __forceinline__ float bf_hi(unsigned u) { return __uint_as_float(u & 0xffff0000u); }

// ---------------- init: pack gc1_W into B-fragments + zero cnt/hgs ----------------
// Bf slot idx = ct*256 + kc*64 + lane: Bf[idx][e] = W[kc*32+(lane>>4)*8+e][ct*16+(lane&15)]
__global__ void k_packB_init(const float* __restrict__ W, unsigned short* __restrict__ Bf,
                             int* __restrict__ cnt, float* __restrict__ hgs) {
    int idx = blockIdx.x * 256 + threadIdx.x;
    if (idx < NCT * 4 * 64) {
        int lane = idx & 63;
        int kc = (idx >> 6) & 3;
        int ct = idx >> 8;
        int col = ct * 16 + (lane & 15);
        int k0 = kc * 32 + (lane >> 4) * 8;
        unsigned short* outp = Bf + (size_t)idx * 8;
        #pragma unroll
        for (int e = 0; e < 8; ++e) {
            float v = (col < C1) ? W[(k0 + e) * C1 + col] : 0.f;
            outp[e] = f2bf(v);
        }
    }
    if (idx < NN) cnt[idx] = 0;
    if (idx < NB * C2) hgs[idx] = 0.f;
}

// ---------------- fused front: gemm1 (MFMA) || fillpos (atomic CSR pass 1) ----------------
__global__ __launch_bounds__(256) void k_front(const float* __restrict__ feat,
                                               const unsigned short* __restrict__ Bf,
                                               unsigned short* __restrict__ t1h,
                                               const int* __restrict__ dst,
                                               int* __restrict__ cnt,
                                               int* __restrict__ pos) {
    if (blockIdx.x >= GB1) {
        int e = (blockIdx.x - GB1) * 256 + threadIdx.x;
        if (e < NE) pos[e] = atomicAdd(&cnt[dst[e]], 1);
        return;
    }
    __shared__ sh8 sB[NCT][4][64];       // 28 KB
    const int tid = threadIdx.x;
    {
        const uint4* srcp = (const uint4*)Bf;
        uint4* dstp = (uint4*)&sB[0][0][0];
        for (int i = tid; i < NCT * 4 * 64; i += 256) dstp[i] = srcp[i];
    }
    __syncthreads();
    const int w = tid >> 6, lane = tid & 63;
    const int ri = lane & 15;            // A row within tile / D col low
    const int kg = lane >> 4;            // 0..3
    for (int tile = blockIdx.x * 4 + w; tile < NTILE; tile += GB1 * 4) {
        const int n = tile * 16 + ri;
        f32x4 acc[NCT];
        #pragma unroll
        for (int ct = 0; ct < NCT; ++ct) acc[ct] = (f32x4){0.f, 0.f, 0.f, 0.f};
        #pragma unroll
        for (int kc = 0; kc < 4; ++kc) {
            const float* ap = feat + (size_t)n * DIN + kc * 32 + kg * 8;
            float4 a0 = *(const float4*)ap;
            float4 a1 = *(const float4*)(ap + 4);
            union { sh8 v; unsigned short u[8]; } af;
            af.u[0] = f2bf(a0.x); af.u[1] = f2bf(a0.y);
            af.u[2] = f2bf(a0.z); af.u[3] = f2bf(a0.w);
            af.u[4] = f2bf(a1.x); af.u[5] = f2bf(a1.y);
            af.u[6] = f2bf(a1.z); af.u[7] = f2bf(a1.w);
            #pragma unroll
            for (int ct = 0; ct < NCT; ++ct)
                acc[ct] = __builtin_amdgcn_mfma_f32_16x16x32_bf16(
                    af.v, sB[ct][kc][lane], acc[ct], 0, 0, 0);
        }
        const int rbase = tile * 16 + kg * 4;
        #pragma unroll
        for (int ct = 0; ct < NCT; ++ct) {
            int col = ct * 16 + ri;
            if (col < C1) {
                #pragma unroll
                for (int r = 0; r < 4; ++r)
                    t1h[(size_t)(rbase + r) * C1 + col] = f2bf(acc[ct][r]);
            }
        }
    }
}

// ---------------- scan of cnt -> rp_part (block-local) + bsum ----------------
__global__ void k_scan1(const int* __restrict__ cnt, int* __restrict__ rp_part,
                        int* __restrict__ bsum) {
    __shared__ int wsum[4];
    const int tid = threadIdx.x;          // 256
    const int lane = tid & 63, wid = tid >> 6;
    int i = blockIdx.x * 256 + tid;
    int v = (i < NN) ? cnt[i] : 0;
    int x = v;
    #pragma unroll
    for (int d = 1; d < 64; d <<= 1) {
        int t = __shfl_up(x, d, 64);
        if (lane >= d) x += t;
    }
    if (lane == 63) wsum[wid] = x;
    __syncthreads();
    int wpref = 0;
    #pragma unroll
    for (int w = 0; w < 4; ++w) if (w < wid) wpref += wsum[w];
    if (i < NN) rp_part[i] = wpref + x - v;
    if (tid == 255) bsum[blockIdx.x] = wpref + x;
}

__global__ void k_scan2(int* __restrict__ bsum, int* __restrict__ row_ptr) {
    __shared__ int wsum[4];
    const int tid = threadIdx.x;
    const int lane = tid & 63, wid = tid >> 6;
    int v = (tid < SCB) ? bsum[tid] : 0;
    int x = v;
    #pragma unroll
    for (int d = 1; d < 64; d <<= 1) {
        int t = __shfl_up(x, d, 64);
        if (lane >= d) x += t;
    }
    if (lane == 63) wsum[wid] = x;
    __syncthreads();
    int wpref = 0;
    #pragma unroll
    for (int w = 0; w < 4; ++w) if (w < wid) wpref += wsum[w];
    if (tid < SCB) bsum[tid] = wpref + x - v;
    if (tid == 255) row_ptr[NN] = wpref + x;
}

// ---------------- fused: finalize row_ptr + scatter (no atomics) ----------------
__global__ void k_scat3(const int* __restrict__ src, const int* __restrict__ dst,
                        const int* __restrict__ rp_part, const int* __restrict__ bsum,
                        const int* __restrict__ pos, int* __restrict__ elist,
                        int* __restrict__ row_ptr) {
    int i = blockIdx.x * 256 + threadIdx.x;
    if (i < NN) row_ptr[i] = rp_part[i] + bsum[i >> 8];
    if (i < NE) {
        int d = dst[i];
        elist[rp_part[d] + bsum[d >> 8] + pos[i]] = src[i];
    }
}

// ---------------- agg1: CSR gather-mean + bias + relu -> packed bf16 h1b ----------------
__global__ __launch_bounds__(256) void k_agg1(const unsigned* __restrict__ t1b,
                                              const int* __restrict__ row_ptr,
                                              const int* __restrict__ elist,
                                              const float* __restrict__ b1,
                                              unsigned* __restrict__ h1b) {
    const int tid = threadIdx.x;
    const int w = tid >> 6, l = tid & 63;
    const int n = blockIdx.x * 4 + w;
    if (n >= NN || l >= 50) return;
    const int e0 = row_ptr[n], e1 = row_ptr[n + 1];
    float acc0 = 0.f, acc1 = 0.f;
    int e = e0;
    for (; e + 7 < e1; e += 8) {
        int s0 = elist[e],     s1 = elist[e + 1], s2 = elist[e + 2], s3 = elist[e + 3];
        int s4 = elist[e + 4], s5 = elist[e + 5], s6 = elist[e + 6], s7 = elist[e + 7];
        unsigned u0 = t1b[(size_t)s0 * 50 + l];
        unsigned u1 = t1b[(size_t)s1 * 50 + l];
        unsigned u2 = t1b[(size_t)s2 * 50 + l];
        unsigned u3 = t1b[(size_t)s3 * 50 + l];
        unsigned u4 = t1b[(size_t)s4 * 50 + l];
        unsigned u5 = t1b[(size_t)s5 * 50 + l];
        unsigned u6 = t1b[(size_t)s6 * 50 + l];
        unsigned u7 = t1b[(size_t)s7 * 50 + l];
        acc0 += bf_lo(u0); acc1 += bf_hi(u0);
        acc0 += bf_lo(u1); acc1 += bf_hi(u1);
        acc0 += bf_lo(u2); acc1 += bf_hi(u2);
        acc0 += bf_lo(u3); acc1 += bf_hi(u3);
        acc0 += bf_lo(u4); acc1 += bf_hi(u4);
        acc0 += bf_lo(u5); acc1 += bf_hi(u5);
        acc0 += bf_lo(u6); acc1 += bf_hi(u6);
        acc0 += bf_lo(u7); acc1 += bf_hi(u7);
    }
    for (; e + 3 < e1; e += 4) {
        int s0 = elist[e], s1 = elist[e + 1], s2 = elist[e + 2], s3 = elist[e + 3];
        unsigned u0 = t1b[(size_t)s0 * 50 + l];
        unsigned u1 = t1b[(size_t)s1 * 50 + l];
        unsigned u2 = t1b[(size_t)s2 * 50 + l];
        unsigned u3 = t1b[(size_t)s3 * 50 + l];
        acc0 += bf_lo(u0); acc1 += bf_hi(u0);
        acc0 += bf_lo(u1); acc1 += bf_hi(u1);
        acc0 += bf_lo(u2); acc1 += bf_hi(u2);
        acc0 += bf_lo(u3); acc1 += bf_hi(u3);
    }
    for (; e < e1; ++e) {
        unsigned u = t1b[(size_t)elist[e] * 50 + l];
        acc0 += bf_lo(u); acc1 += bf_hi(u);
    }
    int deg = e1 - e0;
    float d = (float)(deg > 0 ? deg : 1);
    float v0 = fmaxf(acc0 / d + b1[2 * l], 0.f);
    float v1 = fmaxf(acc1 / d + b1[2 * l + 1], 0.f);
    h1b[(size_t)n * 50 + l] = (unsigned)f2bf(v0) | ((unsigned)f2bf(v1) << 16);
}

// ---------------- GCN layer 2 GEMM: t2 = h1 @ gc2_W ----------------
__global__ void k_gemm2(const unsigned* __restrict__ h1b, const float* __restrict__ W,
                        float* __restrict__ t2) {
    __shared__ float sW[C1 * C2];       // 8 KB
    __shared__ float sr[16][C1];        // 6.4 KB
    for (int idx = threadIdx.x; idx < C1 * C2; idx += 320) sW[idx] = W[idx];
    int ln = threadIdx.x / C2, j = threadIdx.x % C2;   // ln<16
    int n0 = blockIdx.x * 16;
    for (int idx = threadIdx.x; idx < 16 * 50; idx += 320) {
        int r = idx / 50, c = idx % 50;
        int n = n0 + r;
        unsigned u = (n < NN) ? h1b[(size_t)n * 50 + c] : 0u;
        sr[r][2 * c] = bf_lo(u);
        sr[r][2 * c + 1] = bf_hi(u);
    }
    __syncthreads();
    int n = n0 + ln;
    if (n < NN && ln < 16) {
        float acc = 0.f;
        #pragma unroll 4
        for (int k = 0; k < C1; ++k) acc += sr[ln][k] * sW[k * C2 + j];
        t2[(size_t)n * C2 + j] = acc;
    }
}

// ---------------- fused: agg2 (mean+bias+relu) + graph pool (atomic) ----------------
__global__ void k_agg2p(const float* __restrict__ t2, const int* __restrict__ row_ptr,
                        const int* __restrict__ elist, const float* __restrict__ bias,
                        const int* __restrict__ gid, float* __restrict__ hgs) {
    int ln = threadIdx.x / C2, c = threadIdx.x % C2;
    if (ln >= 12) return;
    int n = blockIdx.x * 12 + ln;
    if (n >= NN) return;
    int e0 = row_ptr[n], e1 = row_ptr[n + 1];
    float acc = 0.f;
    int e = e0;
    for (; e + 1 < e1; e += 2) {
        int s0 = elist[e], s1 = elist[e + 1];
        acc += t2[(size_t)s0 * C2 + c];
        acc += t2[(size_t)s1 * C2 + c];
    }
    for (; e < e1; ++e) acc += t2[(size_t)elist[e] * C2 + c];
    int deg = e1 - e0;
    float d = (float)(deg > 0 ? deg : 1);
    float v = acc / d + bias[c];
    v = v > 0.f ? v : 0.f;
    atomicAdd(&hgs[gid[n] * C2 + c], v);
}

// ---------------- fused per-graph tail: hg div (bsearch cnt) + attn head + d1ext prep ----------------
__global__ void k_headp(const float* __restrict__ hgs, const int* __restrict__ gid,
                        const float* __restrict__ desc2d,
                        const float* __restrict__ pgW, const float* __restrict__ pgb,
                        const float* __restrict__ p2W, const float* __restrict__ p2b,
                        const float* __restrict__ W2,
                        float* __restrict__ hg, float* __restrict__ d1ext) {
    __shared__ float shg[C2];
    __shared__ float sg[DHH];
    __shared__ float sa;
    int b = blockIdx.x, j = threadIdx.x;   // 64 threads
    int lo = 0, hi = NN;
    while (lo < hi) { int m = (lo + hi) >> 1; if (gid[m] < b) lo = m + 1; else hi = m; }
    int lo2 = lo, hi2 = NN;
    while (lo2 < hi2) { int m = (lo2 + hi2) >> 1; if (gid[m] < b + 1) lo2 = m + 1; else hi2 = m; }
    float dcnt = (float)(lo2 - lo);
    if (dcnt < 1.f) dcnt = 1.f;
    if (j < C2) {
        float v = hgs[b * C2 + j] / dcnt;
        hg[b * C2 + j] = v;
        shg[j] = v;
    }
    __syncthreads();
    float hgj = pgb[j];
    #pragma unroll
    for (int k = 0; k < C2; ++k) hgj += shg[k] * pgW[k * DHH + j];
    float hdj = p2b[j];
    #pragma unroll 4
    for (int k = 0; k < DD2; ++k) hdj += desc2d[b * DD2 + k] * p2W[k * DHH + j];
    sg[j] = hgj;
    __syncthreads();
    float tj = 0.f;
    #pragma unroll 4
    for (int k = 0; k < DHH; ++k) tj += sg[k] * W2[k * DHH + j];
    float v = tj * hdj;
    #pragma unroll
    for (int off = 32; off; off >>= 1) v += __shfl_xor(v, off, 64);
    if (j == 0) sa = 1.f / (1.f + expf(-v));
    __syncthreads();
    float a = sa;
    for (int k = j; k < KDP; k += 64) {
        float vv = (k < DD2) ? a * desc2d[b * DD2 + k] : (k == DD2 ? 1.f : 0.f);
        d1ext[b * KDP + k] = vv;
    }
}

// ---------------- fc1 via rank-1 factorization ----------------
__global__ __launch_bounds__(256, 2) void k_fc1(const float* __restrict__ d1ext,
                                                const float* __restrict__ W1,
                                                float* __restrict__ U) {
    __shared__ float S[64][KDP];
    const int i = blockIdx.y;
    const int bt = blockIdx.x >> 1;
    const int half = blockIdx.x & 1;
    const int tid = threadIdx.x;
    const int c = tid & 31;
    const int rg = tid >> 5;

    {
        const float4* srcp = (const float4*)(d1ext + (size_t)bt * 64 * KDP);
        float4* dstp = (float4*)&S[0][0];
        for (int idx = tid; idx < 64 * (KDP / 4); idx += 256) dstp[idx] = srcp[idx];
    }
    __syncthreads();

    float acc[8][2];
    #pragma unroll
    for (int r = 0; r < 8; ++r) { acc[r][0] = 0.f; acc[r][1] = 0.f; }

    const float* Wb = W1 + (size_t)i * (KD * HH1) + half * 64 + c;
    for (int k = 0; k < 200; k += 4) {
        const float* Wk = Wb + (size_t)k * HH1;
        float w0[2], w1[2], w2[2], w3[2];
        #pragma unroll
        for (int m = 0; m < 2; ++m) {
            w0[m] = Wk[32 * m];
            w1[m] = Wk[HH1 + 32 * m];
            w2[m] = Wk[2 * HH1 + 32 * m];
            w3[m] = Wk[3 * HH1 + 32 * m];
        }
        #pragma unroll
        for (int r = 0; r < 8; ++r) {
            float4 a4 = *(const float4*)&S[rg * 8 + r][k];
            #pragma unroll
            for (int m = 0; m < 2; ++m)
                acc[r][m] += a4.x * w0[m] + a4.y * w1[m] + a4.z * w2[m] + a4.w * w3[m];
        }
    }
    {
        const float* Wk = Wb + (size_t)200 * HH1;
        float wl0 = Wk[0], wl1 = Wk[32];
        #pragma unroll
        for (int r = 0; r < 8; ++r) {
            float av = S[rg * 8 + r][200];
            acc[r][0] += av * wl0;
            acc[r][1] += av * wl1;
        }
    }
    #pragma unroll
    for (int r = 0; r < 8; ++r) {
        int b = bt * 64 + rg * 8 + r;
        float* Ur = U + (size_t)b * NU + i * HH1 + half * 64 + c;
        Ur[0] = acc[r][0];
        Ur[32] = acc[r][1];
    }
}

__global__ void k_fc1b(const float* __restrict__ U, const float* __restrict__ hg,
                       float* __restrict__ o1) {
    int idx = blockIdx.x * 256 + threadIdx.x;   // 65536
    int b = idx >> 7, j = idx & 127;
    const float* Ub = U + (size_t)b * NU + j;
    const float* hgb = hg + b * C2;
    float acc = Ub[20 * HH1];
    #pragma unroll
    for (int i = 0; i < 20; ++i) acc += hgb[i] * Ub[i * HH1];
    o1[idx] = acc;
}

// ---------------- batch-norm stats ----------------
__global__ void k_bnstats(const float* __restrict__ x, float* __restrict__ stats,
                          int ncols, int nrows) {
    __shared__ float sh[1024], sh2[1024];
    const int tid = threadIdx.x;
    const int j = tid % ncols;
    const int r = tid / ncols;
    const int R = 1024 / ncols;
    float s = 0.f, s2 = 0.f;
    for (int b = r; b < nrows; b += R) {
        float v = x[b * ncols + j];
        s += v; s2 += v * v;
    }
    sh[tid] = s; sh2[tid] = s2;
    __syncthreads();
    if (r == 0) {
        for (int q = 1; q < R; ++q) { s += sh[q * ncols + j]; s2 += sh2[q * ncols + j]; }
        float mu = s / nrows;
        float var = s2 / nrows - mu * mu;
        stats[j] = mu;
        stats[ncols + j] = rsqrtf(var + 1e-5f);
    }
}

// ---------------- fc2 (bn1 + relu fused) ----------------
__global__ void k_fc2(const float* __restrict__ o1, const float* __restrict__ st1,
                      const float* __restrict__ g, const float* __restrict__ beta,
                      const float* __restrict__ W, float* __restrict__ o2) {
    __shared__ float r[HH1];
    __shared__ float part[4][HH2];
    int b = blockIdx.x;
    int tid = threadIdx.x;   // 128
    float v = o1[b * HH1 + tid];
    float nv = (v - st1[tid]) * st1[HH1 + tid] * g[tid] + beta[tid];
    r[tid] = fmaxf(nv, 0.f);
    __syncthreads();
    int m = tid & 31, p = tid >> 5;
    float acc = 0.f;
    #pragma unroll 4
    for (int j = p * 32; j < p * 32 + 32; ++j) acc += r[j] * W[j * HH2 + m];
    part[p][m] = acc;
    __syncthreads();
    if (tid < HH2) o2[b * HH2 + tid] = part[0][tid] + part[1][tid] + part[2][tid] + part[3][tid];
}

// ---------------- bn2 + relu + fc3 ----------------
__global__ void k_final(const float* __restrict__ o2, const float* __restrict__ st2,
                        const float* __restrict__ g, const float* __restrict__ beta,
                        const float* __restrict__ W3, const float* __restrict__ b3,
                        float* __restrict__ out) {
    int b = threadIdx.x;    // 512
    if (b < NB) {
        float acc = b3[0];
        #pragma unroll 4
        for (int m = 0; m < HH2; ++m) {
            float v = o2[b * HH2 + m];
            float nv = (v - st2[m]) * st2[HH2 + m] * g[m] + beta[m];
            acc += fmaxf(nv, 0.f) * W3[m];
        }
        out[b] = acc;
    }
}

extern "C" void kernel_launch(void* const* d_in, const int* in_sizes, int n_in,
                              void* d_out, int out_size, void* d_ws, size_t ws_size,
                              hipStream_t stream) {
    const float* feat   = (const float*)d_in[0];
    const float* desc2d = (const float*)d_in[1];
    const float* gc1W = (const float*)d_in[3];
    const float* gc1b = (const float*)d_in[4];
    const float* gc2W = (const float*)d_in[5];
    const float* gc2b = (const float*)d_in[6];
    const float* pgW  = (const float*)d_in[7];
    const float* pgb  = (const float*)d_in[8];
    const float* p2W  = (const float*)d_in[9];
    const float* p2b  = (const float*)d_in[10];
    const float* W2   = (const float*)d_in[11];
    const float* fc1W = (const float*)d_in[12];
    const float* fc2W = (const float*)d_in[14];
    const float* fc3W = (const float*)d_in[16];
    const float* fc3b = (const float*)d_in[17];
    const float* bn1g = (const float*)d_in[18];
    const float* bn1b = (const float*)d_in[19];
    const float* bn2g = (const float*)d_in[20];
    const float* bn2b = (const float*)d_in[21];
    const int* src = (const int*)d_in[22];
    const int* dst = (const int*)d_in[23];
    const int* gid = (const int*)d_in[24];
    float* out = (float*)d_out;

    char* ws = (char*)d_ws;
    size_t off = 0;
    auto alloc = [&](size_t nb) {
        void* p = ws + off;
        off = (off + nb + 255) & ~(size_t)255;
        return p;
    };
    unsigned* t1b = (unsigned*)alloc((size_t)NN * 50 * 4);   // 10 MB packed bf16 (= [NN][100] bf16)
    unsigned* h1b = (unsigned*)alloc((size_t)NN * 50 * 4);   // 10 MB packed bf16
    float* t2    = (float*)alloc((size_t)NN * C2 * 4);       // 4 MB
    int* cnt_in  = (int*)alloc((size_t)NN * 4);
    int* rp_part = (int*)alloc((size_t)NN * 4);
    int* row_ptr = (int*)alloc((size_t)(NN + 1) * 4);
    int* pos     = (int*)alloc((size_t)NE * 4);
    int* elist   = (int*)alloc((size_t)NE * 4);
    int* bsum    = (int*)alloc((size_t)256 * 4);
    unsigned short* Bf = (unsigned short*)alloc((size_t)NCT * 4 * 64 * 16);  // 28 KB
    float* hgs   = (float*)alloc((size_t)NB * C2 * 4);
    float* hg    = (float*)alloc((size_t)NB * C2 * 4);
    float* o1    = (float*)alloc((size_t)NB * HH1 * 4);
    float* st1   = (float*)alloc(2 * HH1 * 4);
    float* o2    = (float*)alloc((size_t)NB * HH2 * 4);
    float* st2   = (float*)alloc(2 * HH2 * 4);
    // fc1 scratch aliases t1b (dead after k_agg1)
    float* U     = (float*)t1b;                              // 5.5 MB < 10 MB
    float* d1ext = U + (size_t)NB * NU;

    k_packB_init<<<SCB, 256, 0, stream>>>(gc1W, Bf, cnt_in, hgs);
    k_front<<<GB1 + FPB, 256, 0, stream>>>(feat, Bf, (unsigned short*)t1b, dst, cnt_in, pos);
    k_scan1<<<SCB, 256, 0, stream>>>(cnt_in, rp_part, bsum);
    k_scan2<<<1, 256, 0, stream>>>(bsum, row_ptr);
    k_scat3<<<(NE + 255) / 256, 256, 0, stream>>>(src, dst, rp_part, bsum, pos, elist, row_ptr);

    k_agg1<<<(NN + 3) / 4, 256, 0, stream>>>(t1b, row_ptr, elist, gc1b, h1b);
    k_gemm2<<<(NN + 15) / 16, 320, 0, stream>>>(h1b, gc2W, t2);
    k_agg2p<<<(NN + 11) / 12, 256, 0, stream>>>(t2, row_ptr, elist, gc2b, gid, hgs);

    k_headp<<<NB, 64, 0, stream>>>(hgs, gid, desc2d, pgW, pgb, p2W, p2b, W2, hg, d1ext);

    dim3 g1(16, 21);
    k_fc1<<<g1, 256, 0, stream>>>(d1ext, fc1W, U);
    k_fc1b<<<NB * HH1 / 256, 256, 0, stream>>>(U, hg, o1);

    k_bnstats<<<1, 1024, 0, stream>>>(o1, st1, HH1, NB);
    k_fc2<<<NB, 128, 0, stream>>>(o1, st1, bn1g, bn1b, fc2W, o2);
    k_bnstats<<<1, 1024, 0, stream>>>(o2, st2, HH2, NB);
    k_final<<<1, 512, 0, stream>>>(o2, st2, bn2g, bn2b, fc3W, fc3b, out);
}